// Round 5
// baseline (280.080 us; speedup 1.0000x reference)
//
#include <hip/hip_runtime.h>
#include <stdint.h>

// RBF kernel regression: out = exp(-gamma*d2(Xq,Xt)) @ alpha
// out[m] = ea[m] * sum_n w[n] * 2^( S[m][n] ),  S = (2*gamma*log2e*Xq).Xt^T
// bf16 MFMA fp32-acc; w[n]=alpha[n]*exp(-g|Xt_n|^2), ea[m]=exp(-g|Xq_m|^2)
//
// R5 model (fits R1-R4): fabric bytes = NSPLIT*4MB (A refetch) + staged-B misses,
// dur ~= fabric/3TB/s. BM 512 (1024-thd, 16 waves) halves staging to 64 MB;
// BK=128 (64 MFMA/wave per barrier) amortizes the vmcnt drain at 1 block/CU;
// A-frag load overlapped with stage-0 DMA; XCD swizzle: 4my x 8nx = 3MB/XCD L2 set.

#define MM 8192
#define NN 8192
#define DD 256
#define GAMMA (1.0f/256.0f)
#define LOG2E 1.44269504088896340736f
#define SCALE_A (2.0f*GAMMA*LOG2E)
#define NEG_G_LOG2E (-GAMMA*LOG2E)

#define BM 512
#define BN 128
#define NSPLIT 16
#define NPB (NN/NSPLIT)        // 512 cols per block
#define NSTAGES ((NPB/BN)*2)   // 8 stages of BK=128

typedef __bf16 bf16x8 __attribute__((ext_vector_type(8)));
typedef float  f32x4  __attribute__((ext_vector_type(4)));

// ws: [0,4MB) A bf16 scaled row-major; [4MB,8MB) B staged [s:4][n:8192][g':8]x16B,
//     g' = g ^ (n&7) bank swizzle; [8MB,+32K) w; [+32K,+32K) ea; then part[16][8192] f32
#define A_OFF  ((size_t)0)
#define B_OFF  ((size_t)4 << 20)
#define W_OFF  ((size_t)8 << 20)
#define EA_OFF (((size_t)8 << 20) + 32768)
#define PART_OFF (((size_t)8 << 20) + 65536)

__device__ __forceinline__ unsigned short f2bf(float f) {  // RNE f32->bf16
  union { float f; uint32_t u; } x; x.f = f;
  uint32_t u = x.u;
  u += 0x7FFFu + ((u >> 16) & 1u);
  return (unsigned short)(u >> 16);
}
__device__ __forceinline__ uint32_t pack2(float a, float b) {
  return (uint32_t)f2bf(a) | ((uint32_t)f2bf(b) << 16);
}

__device__ __forceinline__ void async_ld16(void* lds, const void* g) {
  __builtin_amdgcn_global_load_lds(
      (const __attribute__((address_space(1))) uint32_t*)g,
      (__attribute__((address_space(3))) uint32_t*)lds, 16, 0, 0);
}

__global__ __launch_bounds__(256) void prep_kernel(
    const float* __restrict__ Xq, const float* __restrict__ Xt,
    const float* __restrict__ alpha,
    unsigned short* __restrict__ Aq, char* __restrict__ Bst,
    float* __restrict__ w, float* __restrict__ ea)
{
  const int lane = threadIdx.x & 63;
  const int gw = (blockIdx.x << 2) + (threadIdx.x >> 6);
  if (gw < MM) {                       // ---- A: one wave per row, coalesced
    const int row = gw;
    const float4 v = *(const float4*)(Xq + (size_t)row * DD + lane * 4);
    float ss = v.x*v.x + v.y*v.y + v.z*v.z + v.w*v.w;
#pragma unroll
    for (int off = 32; off; off >>= 1) ss += __shfl_xor(ss, off, 64);
    ushort4 p;
    p.x = f2bf(v.x * SCALE_A); p.y = f2bf(v.y * SCALE_A);
    p.z = f2bf(v.z * SCALE_A); p.w = f2bf(v.w * SCALE_A);
    *(ushort4*)(Aq + (size_t)row * DD + lane * 4) = p;
    if (lane == 0) ea[row] = __builtin_amdgcn_exp2f(NEG_G_LOG2E * ss);
  } else {                             // ---- B: one wave per 8 cols, 16B/lane stores
    const int widx = gw - MM;          // 0..1023
    const int n  = widx * 8 + (lane >> 3);
    const int gq = lane & 7;           // storage granule g'
    const int g  = gq ^ (n & 7);       // logical granule (k = s*64 + g*8 .. +8)
    float ss = 0.f;
#pragma unroll
    for (int s = 0; s < 4; ++s) {
      const float* src = Xt + (size_t)n * DD + s * 64 + g * 8;
      const float4 f0 = *(const float4*)(src);
      const float4 f1 = *(const float4*)(src + 4);
      ss += f0.x*f0.x + f0.y*f0.y + f0.z*f0.z + f0.w*f0.w
          + f1.x*f1.x + f1.y*f1.y + f1.z*f1.z + f1.w*f1.w;
      uint4 pk;
      pk.x = pack2(f0.x, f0.y); pk.y = pack2(f0.z, f0.w);
      pk.z = pack2(f1.x, f1.y); pk.w = pack2(f1.z, f1.w);
      *(uint4*)(Bst + (((size_t)(s * NN + n) * 8 + gq) << 4)) = pk;  // 1KB run/wave
    }
    ss += __shfl_xor(ss, 1, 64);       // reduce across the 8 lanes of col n
    ss += __shfl_xor(ss, 2, 64);
    ss += __shfl_xor(ss, 4, 64);
    if (gq == 0) w[n] = alpha[n] * __builtin_amdgcn_exp2f(NEG_G_LOG2E * ss);
  }
}

__global__ __launch_bounds__(1024) void rbf_main(   // 16 waves = 1 block/CU
    const unsigned short* __restrict__ Aq, const char* __restrict__ Bst,
    const float* __restrict__ w, const float* __restrict__ ea,
    float* __restrict__ part)
{
  __shared__ char lds[2 * 32768];      // dbuf: 32 KB/stage = 128 cols x 128 k x bf16
  const int tid  = threadIdx.x;
  const int wave = tid >> 6, lane = tid & 63;   // 16 waves
  const int quad = lane >> 4, l16 = lane & 15;

  // XCD partition: grid 256 = 16 my x 16 nx; xcd b&7 gets 4 my x 8 nx
  //   -> per-XCD L2 set = 1MB A + 2MB B <= 4MB
  const int b    = blockIdx.x;
  const int xcd  = b & 7, slot = b >> 3;             // slot 0..31
  const int my   = (xcd & 3) * 4 + (slot & 3);       // 0..15
  const int nx   = (xcd >> 2) * 8 + (slot >> 2);     // 0..15
  const int mblk   = my * BM;
  const int nbase0 = nx * NPB;

  auto issue = [&](int st) {           // stage BK=128: two 16KB halves (s-chunks)
    const int ntile = st >> 1, s2 = st & 1;
    char* l0 = lds + (st & 1) * 32768 + wave * 1024;  // wave-uniform base
    const int col0 = nbase0 + ntile * BN + wave * 8;  // 8 cols x 128 B per wave
#pragma unroll
    for (int h = 0; h < 2; ++h) {
      const int s = s2 * 2 + h;
      const char* g = Bst + ((size_t)(s * NN + col0) << 7) + (size_t)lane * 16;
      async_ld16(l0 + h * 16384, g);
    }
  };

  issue(0);  // in flight while A-fragments load below

  // A fragments register-resident for full K=256 (32 rows/wave)
  bf16x8 afrag[2][8];
#pragma unroll
  for (int rt = 0; rt < 2; ++rt)
#pragma unroll
    for (int kc = 0; kc < 8; ++kc) {
      union { uint4 u; bf16x8 v; } cv;
      cv.u = *(const uint4*)(Aq + (size_t)(mblk + wave * 32 + rt * 16 + l16) * DD
                                 + kc * 32 + quad * 8);
      afrag[rt][kc] = cv.v;
    }

  const f32x4 fzero = {0.f, 0.f, 0.f, 0.f};
  f32x4 acc[2][8];
#pragma unroll
  for (int rt = 0; rt < 2; ++rt)
#pragma unroll
    for (int ct = 0; ct < 8; ++ct) acc[rt][ct] = fzero;
  float outacc[2][4] = {{0.f,0.f,0.f,0.f},{0.f,0.f,0.f,0.f}};

  for (int st = 0; st < NSTAGES; ++st) {
    __syncthreads();                   // buf[st&1] staged & prior reads drained
    if (st + 1 < NSTAGES) issue(st + 1);
    const char* buf = lds + (st & 1) * 32768;
    const int s2 = st & 1;
#pragma unroll
    for (int kcL = 0; kcL < 4; ++kcL) {
      const int kc = s2 * 4 + kcL;     // afrag k-chunk (k = kc*32)
      const int h  = kcL >> 1;         // 16KB half within the stage
#pragma unroll
      for (int ct = 0; ct < 8; ++ct) {
        const int gp = (((kcL & 1) * 4 + quad)) ^ (l16 & 7);  // bank swizzle <=2-way
        union { uint4 u; bf16x8 v; } cv;
        cv.u = *(const uint4*)(buf + h * 16384 + (ct * 16 + l16) * 128 + gp * 16);
        acc[0][ct] = __builtin_amdgcn_mfma_f32_16x16x32_bf16(afrag[0][kc], cv.v, acc[0][ct], 0, 0, 0);
        acc[1][ct] = __builtin_amdgcn_mfma_f32_16x16x32_bf16(afrag[1][kc], cv.v, acc[1][ct], 0, 0, 0);
      }
    }
    if (s2 == 1) {  // finished 128-col tile: C/D row=quad*4+reg, col=l16
      const int nb = nbase0 + (st >> 1) * BN;
#pragma unroll
      for (int ct = 0; ct < 8; ++ct) {
        const float wv = w[nb + ct * 16 + l16];
#pragma unroll
        for (int rt = 0; rt < 2; ++rt) {
          f32x4 a = acc[rt][ct];
          outacc[rt][0] += wv * __builtin_amdgcn_exp2f(a[0]);
          outacc[rt][1] += wv * __builtin_amdgcn_exp2f(a[1]);
          outacc[rt][2] += wv * __builtin_amdgcn_exp2f(a[2]);
          outacc[rt][3] += wv * __builtin_amdgcn_exp2f(a[3]);
          acc[rt][ct] = fzero;
        }
      }
    }
  }

  // reduce across l16, write exclusive per-block partials (no atomics)
#pragma unroll
  for (int rt = 0; rt < 2; ++rt)
#pragma unroll
    for (int i = 0; i < 4; ++i) {
      float v = outacc[rt][i];
      v += __shfl_xor(v, 1, 64);
      v += __shfl_xor(v, 2, 64);
      v += __shfl_xor(v, 4, 64);
      v += __shfl_xor(v, 8, 64);
      if (l16 == 0) {
        const int row = mblk + wave * 32 + rt * 16 + quad * 4 + i;
        part[(size_t)nx * MM + row] = ea[row] * v;
      }
    }
}

__global__ __launch_bounds__(256) void reduce_kernel(
    const float* __restrict__ part, float* __restrict__ out)
{
  const int row = blockIdx.x * 256 + threadIdx.x;
  float s = 0.f;
#pragma unroll
  for (int i = 0; i < NSPLIT; ++i) s += part[(size_t)i * MM + row];
  out[row] = s;
}

extern "C" void kernel_launch(void* const* d_in, const int* in_sizes, int n_in,
                              void* d_out, int out_size, void* d_ws, size_t ws_size,
                              hipStream_t stream) {
  const float* Xq    = (const float*)d_in[0];
  const float* Xt    = (const float*)d_in[1];
  const float* alpha = (const float*)d_in[2];
  float* out = (float*)d_out;
  char*  ws  = (char*)d_ws;

  unsigned short* Aq = (unsigned short*)(ws + A_OFF);
  char*  Bst  = ws + B_OFF;
  float* w    = (float*)(ws + W_OFF);
  float* ea   = (float*)(ws + EA_OFF);
  float* part = (float*)(ws + PART_OFF);

  hipLaunchKernelGGL(prep_kernel, dim3((MM + NN / 8) / 4), dim3(256), 0, stream,
                     Xq, Xt, alpha, Aq, Bst, w, ea);
  hipLaunchKernelGGL(rbf_main, dim3(NSPLIT * (MM / BM)), dim3(1024), 0, stream,
                     Aq, Bst, w, ea, part);
  hipLaunchKernelGGL(reduce_kernel, dim3(MM / 256), dim3(256), 0, stream,
                     part, out);
}

// Round 6
// 108.522 us; speedup vs baseline: 2.5809x; 2.5809x over previous
//
#include <hip/hip_runtime.h>
#include <stdint.h>

// RBF kernel regression: out = exp(-gamma*d2(Xq,Xt)) @ alpha
// out[m] = ea[m] * sum_n w[n] * 2^( S[m][n] ),  S = (2*gamma*log2e*Xq).Xt^T
//
// R6: LDS-free MFMA GEMM. R1-R5 showed the global_load_lds + barrier structure
// pins dur at (L2-miss traffic)/~3TB/s with every pipe <20% busy; R5's 1024-thd
// variant additionally spilled (WRITE 377 MB). Fix: pre-pack A and B into
// fragment-linear layout [tile:512][granule:32][lane16:16]x16B so fragment
// loads are coalesced 1KB dwordx4 bursts straight from L2. No LDS, no
// __syncthreads, no DMA. 1024 blocks (64my x 16nx), 4 waves/block, 3 blocks/CU.

#define MM 8192
#define NN 8192
#define DD 256
#define GAMMA (1.0f/256.0f)
#define LOG2E 1.44269504088896340736f
#define SCALE_A (2.0f*GAMMA*LOG2E)
#define NEG_G_LOG2E (-GAMMA*LOG2E)

#define NSPLIT 16
#define NPB (NN/NSPLIT)     // 512 cols per block
#define NT_PER (NPB/16)     // 32 column-tiles of 16

typedef __bf16 bf16x8 __attribute__((ext_vector_type(8)));
typedef float  f32x4  __attribute__((ext_vector_type(4)));

// ws: [0,4MB) A frag-linear; [4MB,8MB) B frag-linear; [8MB,+32K) w;
//     [+32K] ea; [+64K] part[16][8192] f32
#define A_OFF  ((size_t)0)
#define B_OFF  ((size_t)4 << 20)
#define W_OFF  ((size_t)8 << 20)
#define EA_OFF (((size_t)8 << 20) + 32768)
#define PART_OFF (((size_t)8 << 20) + 65536)

__device__ __forceinline__ unsigned short f2bf(float f) {  // RNE f32->bf16
  union { float f; uint32_t u; } x; x.f = f;
  uint32_t u = x.u;
  u += 0x7FFFu + ((u >> 16) & 1u);
  return (unsigned short)(u >> 16);
}
__device__ __forceinline__ uint32_t pack2(float a, float b) {
  return (uint32_t)f2bf(a) | ((uint32_t)f2bf(b) << 16);
}

// One wave per 16-row/col tile. Fragment-linear pack: for tile t, round r,
// lane l writes dst + t*8192 + r*1024 + l*16, holding granule gg=r*4+(l>>4)
// (k=gg*8..+8) of row/col n=t*16+(l&15). Both loads and stores are 1KB runs.
__global__ __launch_bounds__(256) void prep_kernel(
    const float* __restrict__ Xq, const float* __restrict__ Xt,
    const float* __restrict__ alpha,
    char* __restrict__ Amat, char* __restrict__ Bmat,
    float* __restrict__ w, float* __restrict__ ea)
{
  const int lane = threadIdx.x & 63;
  const int gw = blockIdx.x * 4 + (threadIdx.x >> 6);  // 0..1023
  const bool isA = gw < 512;
  const int t = isA ? gw : gw - 512;
  const float* __restrict__ src = isA ? Xq : Xt;
  char* __restrict__ dst = isA ? Amat : Bmat;
  const float sc = isA ? SCALE_A : 1.0f;
  const int n = t * 16 + (lane & 15);
  float ss = 0.f;
#pragma unroll
  for (int r = 0; r < 8; ++r) {
    const int gg = r * 4 + (lane >> 4);
    const float* p = src + (size_t)n * DD + gg * 8;
    const float4 f0 = *(const float4*)p;
    const float4 f1 = *(const float4*)(p + 4);
    ss += f0.x*f0.x + f0.y*f0.y + f0.z*f0.z + f0.w*f0.w
        + f1.x*f1.x + f1.y*f1.y + f1.z*f1.z + f1.w*f1.w;
    uint4 pk;
    pk.x = pack2(f0.x * sc, f0.y * sc); pk.y = pack2(f0.z * sc, f0.w * sc);
    pk.z = pack2(f1.x * sc, f1.y * sc); pk.w = pack2(f1.z * sc, f1.w * sc);
    *(uint4*)(dst + (size_t)t * 8192 + r * 1024 + lane * 16) = pk;
  }
  ss += __shfl_xor(ss, 16, 64);   // reduce the 4 lanes holding col n
  ss += __shfl_xor(ss, 32, 64);
  if (lane < 16) {
    if (isA) ea[n] = __builtin_amdgcn_exp2f(NEG_G_LOG2E * ss);
    else     w[n]  = alpha[n] * __builtin_amdgcn_exp2f(NEG_G_LOG2E * ss);
  }
}

__global__ __launch_bounds__(256, 3) void rbf_main(   // ~150 VGPR, 3 waves/SIMD
    const char* __restrict__ Amat, const char* __restrict__ Bmat,
    const float* __restrict__ w, const float* __restrict__ ea,
    float* __restrict__ part)
{
  const int tid  = threadIdx.x;
  const int wave = tid >> 6, lane = tid & 63;
  const int quad = lane >> 4, l16 = lane & 15;

  // 1024 blocks = 64 my x 16 nx; XCD b&7 gets 16 my x 8 nx
  //   -> per-XCD hot set = 1MB A + 2MB B <= 4MB L2
  const int b    = blockIdx.x;
  const int xcd  = b & 7, slot = b >> 3;             // slot 0..127
  const int my   = (xcd & 3) * 16 + (slot & 15);     // 0..63
  const int nx   = (xcd >> 2) * 8 + (slot >> 4);     // 0..15
  const int mt0    = my * 8 + wave * 2;              // wave: 32 rows = 2 mtiles
  const int nt0    = nx * NT_PER;
  const int nbase0 = nx * NPB;

  // A fragments register-resident for full K=256 (coalesced 1KB loads)
  bf16x8 afrag[2][8];
#pragma unroll
  for (int rt = 0; rt < 2; ++rt)
#pragma unroll
    for (int kc = 0; kc < 8; ++kc) {
      union { uint4 u; bf16x8 v; } cv;
      cv.u = *(const uint4*)(Amat + (size_t)(mt0 + rt) * 8192 + kc * 1024 + lane * 16);
      afrag[rt][kc] = cv.v;
    }

  const f32x4 fzero = {0.f, 0.f, 0.f, 0.f};
  float outacc[2][4] = {{0.f,0.f,0.f,0.f},{0.f,0.f,0.f,0.f}};

  for (int ct = 0; ct < NT_PER; ++ct) {
    union { uint4 u; bf16x8 v; } bf[8];
#pragma unroll
    for (int kc = 0; kc < 8; ++kc)     // 8 independent coalesced 1KB loads (L2)
      bf[kc].u = *(const uint4*)(Bmat + (size_t)(nt0 + ct) * 8192 + kc * 1024 + lane * 16);
    const float wv = w[nbase0 + ct * 16 + l16];
    f32x4 acc[2][2] = {{fzero, fzero}, {fzero, fzero}};   // 2 chains per rt
#pragma unroll
    for (int kc = 0; kc < 8; ++kc) {
      acc[0][kc & 1] = __builtin_amdgcn_mfma_f32_16x16x32_bf16(afrag[0][kc], bf[kc].v, acc[0][kc & 1], 0, 0, 0);
      acc[1][kc & 1] = __builtin_amdgcn_mfma_f32_16x16x32_bf16(afrag[1][kc], bf[kc].v, acc[1][kc & 1], 0, 0, 0);
    }
#pragma unroll
    for (int rt = 0; rt < 2; ++rt) {   // C/D: row=quad*4+reg, col=l16
      const f32x4 s = acc[rt][0] + acc[rt][1];
      outacc[rt][0] += wv * __builtin_amdgcn_exp2f(s[0]);
      outacc[rt][1] += wv * __builtin_amdgcn_exp2f(s[1]);
      outacc[rt][2] += wv * __builtin_amdgcn_exp2f(s[2]);
      outacc[rt][3] += wv * __builtin_amdgcn_exp2f(s[3]);
    }
  }

  // reduce over the 16 columns (l16), write exclusive per-block partials
#pragma unroll
  for (int rt = 0; rt < 2; ++rt)
#pragma unroll
    for (int i = 0; i < 4; ++i) {
      float v = outacc[rt][i];
      v += __shfl_xor(v, 1, 64);
      v += __shfl_xor(v, 2, 64);
      v += __shfl_xor(v, 4, 64);
      v += __shfl_xor(v, 8, 64);
      if (l16 == 0) {
        const int row = my * 128 + wave * 32 + rt * 16 + quad * 4 + i;
        part[(size_t)nx * MM + row] = ea[row] * v;
      }
    }
}

__global__ __launch_bounds__(256) void reduce_kernel(
    const float* __restrict__ part, float* __restrict__ out)
{
  const int row = blockIdx.x * 256 + threadIdx.x;
  float s = 0.f;
#pragma unroll
  for (int i = 0; i < NSPLIT; ++i) s += part[(size_t)i * MM + row];
  out[row] = s;
}

extern "C" void kernel_launch(void* const* d_in, const int* in_sizes, int n_in,
                              void* d_out, int out_size, void* d_ws, size_t ws_size,
                              hipStream_t stream) {
  const float* Xq    = (const float*)d_in[0];
  const float* Xt    = (const float*)d_in[1];
  const float* alpha = (const float*)d_in[2];
  float* out = (float*)d_out;
  char*  ws  = (char*)d_ws;

  char*  Amat = ws + A_OFF;
  char*  Bmat = ws + B_OFF;
  float* w    = (float*)(ws + W_OFF);
  float* ea   = (float*)(ws + EA_OFF);
  float* part = (float*)(ws + PART_OFF);

  hipLaunchKernelGGL(prep_kernel, dim3(256), dim3(256), 0, stream,
                     Xq, Xt, alpha, Amat, Bmat, w, ea);
  hipLaunchKernelGGL(rbf_main, dim3(NSPLIT * 64), dim3(256), 0, stream,
                     Amat, Bmat, w, ea, part);
  hipLaunchKernelGGL(reduce_kernel, dim3(MM / 256), dim3(256), 0, stream,
                     part, out);
}

// Round 7
// 102.139 us; speedup vs baseline: 2.7422x; 1.0625x over previous
//
#include <hip/hip_runtime.h>
#include <stdint.h>

// RBF kernel regression: out = exp(-gamma*d2(Xq,Xt)) @ alpha
// out[m] = ea[m] * sum_n w[n] * 2^( S[m][n] ),  S = (2*gamma*log2e*Xq).Xt^T
//
// R7: LDS-free frag-linear GEMM (R6 structure) + 64 rows/wave (afrag[4][8],
// halves per-CU VMEM B-traffic to ~2.25 MB) + register ping-pong prefetch of
// the B tile (unroll-2 K... ct-loop) to kill the per-ct load->vmcnt->MFMA
// serial stall. NOTE (R1-R5 lesson): global_load_lds staging traffic did NOT
// allocate in L2 (dur pinned at bytes/3TB/s); regular loads hit L1/L2 (R6
// FETCH 146->12 MB). Keep regular loads.

#define MM 8192
#define NN 8192
#define DD 256
#define GAMMA (1.0f/256.0f)
#define LOG2E 1.44269504088896340736f
#define SCALE_A (2.0f*GAMMA*LOG2E)
#define NEG_G_LOG2E (-GAMMA*LOG2E)

#define NSPLIT 16
#define NPB (NN/NSPLIT)     // 512 cols per block
#define NT_PER (NPB/16)     // 32 column-tiles of 16

typedef __bf16 bf16x8 __attribute__((ext_vector_type(8)));
typedef float  f32x4  __attribute__((ext_vector_type(4)));

// ws: [0,4MB) A frag-linear; [4MB,8MB) B frag-linear; [8MB,+32K) w;
//     [+32K] ea; [+64K] part[16][8192] f32
#define A_OFF  ((size_t)0)
#define B_OFF  ((size_t)4 << 20)
#define W_OFF  ((size_t)8 << 20)
#define EA_OFF (((size_t)8 << 20) + 32768)
#define PART_OFF (((size_t)8 << 20) + 65536)

__device__ __forceinline__ unsigned short f2bf(float f) {  // RNE f32->bf16
  union { float f; uint32_t u; } x; x.f = f;
  uint32_t u = x.u;
  u += 0x7FFFu + ((u >> 16) & 1u);
  return (unsigned short)(u >> 16);
}
__device__ __forceinline__ uint32_t pack2(float a, float b) {
  return (uint32_t)f2bf(a) | ((uint32_t)f2bf(b) << 16);
}

// One wave per 16-row/col tile. Fragment-linear pack: tile t, round r, lane l
// writes dst + t*8192 + r*1024 + l*16 holding k-granule g=r*4+(l>>4) of
// row/col n=t*16+(l&15) — exactly the mfma_16x16x32 A/B operand layout.
__global__ __launch_bounds__(256) void prep_kernel(
    const float* __restrict__ Xq, const float* __restrict__ Xt,
    const float* __restrict__ alpha,
    char* __restrict__ Amat, char* __restrict__ Bmat,
    float* __restrict__ w, float* __restrict__ ea)
{
  const int lane = threadIdx.x & 63;
  const int gw = blockIdx.x * 4 + (threadIdx.x >> 6);  // 0..1023
  const bool isA = gw < 512;
  const int t = isA ? gw : gw - 512;
  const float* __restrict__ src = isA ? Xq : Xt;
  char* __restrict__ dst = isA ? Amat : Bmat;
  const float sc = isA ? SCALE_A : 1.0f;
  const int n = t * 16 + (lane & 15);
  float ss = 0.f;
#pragma unroll
  for (int r = 0; r < 8; ++r) {
    const int gg = r * 4 + (lane >> 4);
    const float* p = src + (size_t)n * DD + gg * 8;
    const float4 f0 = *(const float4*)p;
    const float4 f1 = *(const float4*)(p + 4);
    ss += f0.x*f0.x + f0.y*f0.y + f0.z*f0.z + f0.w*f0.w
        + f1.x*f1.x + f1.y*f1.y + f1.z*f1.z + f1.w*f1.w;
    uint4 pk;
    pk.x = pack2(f0.x * sc, f0.y * sc); pk.y = pack2(f0.z * sc, f0.w * sc);
    pk.z = pack2(f1.x * sc, f1.y * sc); pk.w = pack2(f1.z * sc, f1.w * sc);
    *(uint4*)(dst + (size_t)t * 8192 + r * 1024 + lane * 16) = pk;
  }
  ss += __shfl_xor(ss, 16, 64);   // reduce the 4 lanes holding col n
  ss += __shfl_xor(ss, 32, 64);
  if (lane < 16) {
    if (isA) ea[n] = __builtin_amdgcn_exp2f(NEG_G_LOG2E * ss);
    else     w[n]  = alpha[n] * __builtin_amdgcn_exp2f(NEG_G_LOG2E * ss);
  }
}

__global__ __launch_bounds__(256, 2) void rbf_main(
    const char* __restrict__ Amat, const char* __restrict__ Bmat,
    const float* __restrict__ w, const float* __restrict__ ea,
    float* __restrict__ part)
{
  const int tid  = threadIdx.x;
  const int wave = tid >> 6, lane = tid & 63;
  const int quad = lane >> 4, l16 = lane & 15;

  // 512 blocks = 32 my x 16 nx; XCD b&7 gets 8 my x 8 nx
  //   -> per-XCD hot set = 1MB A + 2MB B <= 4MB L2
  const int b    = blockIdx.x;
  const int xcd  = b & 7, slot = b >> 3;             // slot 0..63
  const int my   = (xcd & 3) * 8 + (slot & 7);       // 0..31 (256 rows each)
  const int nx   = (xcd >> 2) * 8 + (slot >> 3);     // 0..15
  const int mt0    = my * 16 + wave * 4;             // 4 mtiles = 64 rows/wave
  const int nt0    = nx * NT_PER;
  const int nbase0 = nx * NPB;

  // A fragments register-resident for full K=256: 4 mtiles x 8 kc = 128 VGPR
  bf16x8 afrag[4][8];
#pragma unroll
  for (int rt = 0; rt < 4; ++rt)
#pragma unroll
    for (int kc = 0; kc < 8; ++kc) {
      union { uint4 u; bf16x8 v; } cv;
      cv.u = *(const uint4*)(Amat + (size_t)(mt0 + rt) * 8192 + kc * 1024 + lane * 16);
      afrag[rt][kc] = cv.v;
    }

  float outacc[4][4] = {{0,0,0,0},{0,0,0,0},{0,0,0,0},{0,0,0,0}};

  uint4 bufA[8], bufB[8];
  auto loadB = [&](uint4* dst, int ct) {
#pragma unroll
    for (int kc = 0; kc < 8; ++kc)
      dst[kc] = *(const uint4*)(Bmat + (size_t)(nt0 + ct) * 8192 + kc * 1024 + lane * 16);
  };

  const f32x4 fzero = {0.f, 0.f, 0.f, 0.f};
  auto compute = [&](const uint4* buf, int ct) {
    const float wv = w[nbase0 + ct * 16 + l16];
    f32x4 acc[4] = {fzero, fzero, fzero, fzero};   // 4 independent 8-deep chains
#pragma unroll
    for (int kc = 0; kc < 8; ++kc) {
      union { uint4 u; bf16x8 v; } cv; cv.u = buf[kc];
#pragma unroll
      for (int rt = 0; rt < 4; ++rt)
        acc[rt] = __builtin_amdgcn_mfma_f32_16x16x32_bf16(afrag[rt][kc], cv.v, acc[rt], 0, 0, 0);
    }
#pragma unroll
    for (int rt = 0; rt < 4; ++rt) {               // C/D: row=quad*4+reg, col=l16
      outacc[rt][0] += wv * __builtin_amdgcn_exp2f(acc[rt][0]);
      outacc[rt][1] += wv * __builtin_amdgcn_exp2f(acc[rt][1]);
      outacc[rt][2] += wv * __builtin_amdgcn_exp2f(acc[rt][2]);
      outacc[rt][3] += wv * __builtin_amdgcn_exp2f(acc[rt][3]);
    }
  };

  loadB(bufA, 0);
  for (int ct = 0; ct < NT_PER; ct += 2) {   // ping-pong: loads for ct+1 issued
    loadB(bufB, ct + 1);                     //   before computing ct
    compute(bufA, ct);
    if (ct + 2 < NT_PER) loadB(bufA, ct + 2);
    compute(bufB, ct + 1);
  }

  // reduce over the 16 columns (l16), write exclusive per-block partials
#pragma unroll
  for (int rt = 0; rt < 4; ++rt)
#pragma unroll
    for (int i = 0; i < 4; ++i) {
      float v = outacc[rt][i];
      v += __shfl_xor(v, 1, 64);
      v += __shfl_xor(v, 2, 64);
      v += __shfl_xor(v, 4, 64);
      v += __shfl_xor(v, 8, 64);
      if (l16 == 0) {
        const int row = my * 256 + wave * 64 + rt * 16 + quad * 4 + i;
        part[(size_t)nx * MM + row] = ea[row] * v;
      }
    }
}

__global__ __launch_bounds__(256) void reduce_kernel(
    const float* __restrict__ part, float* __restrict__ out)
{
  const int row = blockIdx.x * 256 + threadIdx.x;
  float s = 0.f;
#pragma unroll
  for (int i = 0; i < NSPLIT; ++i) s += part[(size_t)i * MM + row];
  out[row] = s;
}

extern "C" void kernel_launch(void* const* d_in, const int* in_sizes, int n_in,
                              void* d_out, int out_size, void* d_ws, size_t ws_size,
                              hipStream_t stream) {
  const float* Xq    = (const float*)d_in[0];
  const float* Xt    = (const float*)d_in[1];
  const float* alpha = (const float*)d_in[2];
  float* out = (float*)d_out;
  char*  ws  = (char*)d_ws;

  char*  Amat = ws + A_OFF;
  char*  Bmat = ws + B_OFF;
  float* w    = (float*)(ws + W_OFF);
  float* ea   = (float*)(ws + EA_OFF);
  float* part = (float*)(ws + PART_OFF);

  hipLaunchKernelGGL(prep_kernel, dim3(256), dim3(256), 0, stream,
                     Xq, Xt, alpha, Amat, Bmat, w, ea);
  hipLaunchKernelGGL(rbf_main, dim3(512), dim3(256), 0, stream,
                     Amat, Bmat, w, ea, part);
  hipLaunchKernelGGL(reduce_kernel, dim3(MM / 256), dim3(256), 0, stream,
                     part, out);
}